// Round 14
// baseline (100.468 us; speedup 1.0000x reference)
//
#include <hip/hip_runtime.h>
#include <math.h>

// CRF forward loss, B=32, S=512, L=64 — chunked-matrix-product formulation.
// Round 14: TLP probe. CL=8 -> 2048 single-wave blocks (2 waves/SIMD; R12
// profile showed 1 wave/SIMD with 95% idle). Fold gets a depth-4 prefetch
// ring (nact<=64 now; 8KB/step matP reads need 3-step latency cover).

constexpr int S_LEN   = 512;
constexpr int NB      = 32;
constexpr int NL      = 64;
constexpr int LL      = 4096;
constexpr int CL      = 8;
constexpr int NCH     = 64;            // chunks per batch
constexpr int NCHUNKS = NB * NCH;      // 2048

#define LN2F 0.69314718055994531f
#define PREF 4.6588830833596715f       /* ln(64)+0.5 : M = exp(E)*e^-PREF */

typedef _Float16 h4 __attribute__((ext_vector_type(4)));
typedef float    f4 __attribute__((ext_vector_type(4)));
union U4 { unsigned u[2]; h4 v; };

__device__ __forceinline__ float bl(float v, int sl) {
  return __int_as_float(__builtin_amdgcn_readlane(__float_as_int(v), sl));
}
__device__ __forceinline__ unsigned pk2(float a, float b) {
  auto r = __builtin_amdgcn_cvt_pkrtz(a, b);
  return __builtin_bit_cast(unsigned, r);
}
__device__ __forceinline__ float expw(float x) {   // exp(x)*e^-PREF, native
  return __expf(x - PREF);
}

// ---------------- Phase 1: chunk products (backward) ----------------
__global__ __launch_bounds__(64) void crf_chunk(
    const float* __restrict__ emits,
    const int*   __restrict__ targets,
    const int*   __restrict__ mask,
    _Float16*    __restrict__ matP,   // [2048][4096] f16
    float*       __restrict__ wsf)    // [0,2048): Lacc ; [2048,4096): gold
{
  const int ci   = blockIdx.x;
  const int b    = ci >> 6;
  const int cc   = ci & 63;
  const int lane = threadIdx.x;
  const int c    = lane & 15;
  const int h    = lane >> 4;
  const float* __restrict__ eb = emits + (size_t)b * (S_LEN * LL);

  // sequence length (mask is a contiguous prefix)
  int len;
  {
    const int* mb = mask + b * S_LEN;
    int cnt = 0;
    #pragma unroll
    for (int i = 0; i < 8; ++i) cnt += (mb[i * 64 + lane] != 0);
    #pragma unroll
    for (int off = 32; off; off >>= 1) cnt += __shfl_xor(cnt, off);
    len = cnt;
  }

  // gold partial: emissions s in [8cc, 8cc+8) ∩ [0,len)
  {
    float g = 0.f;
    const int s = 8 * cc + (lane & 7);
    if (lane < 8 && s < len) {
      const int* tb = targets + b * (S_LEN + 1);
      g = eb[(size_t)s * LL + tb[s] * NL + tb[s + 1]];
    }
    #pragma unroll
    for (int off = 32; off; off >>= 1) g += __shfl_xor(g, off);
    if (lane == 0) wsf[NCHUNKS + ci] = g;
  }

  const int s0 = 8 * cc + 1;
  const int n  = min(len - s0, CL);
  if (n < 1) return;

  // R = Identity in B-frag layout: bf tile(K,J)[i] = (K==J && 4h+i==c)
  h4 bf[4][4];
  #pragma unroll
  for (int K = 0; K < 4; ++K)
    #pragma unroll
    for (int J = 0; J < 4; ++J) {
      h4 v;
      #pragma unroll
      for (int i = 0; i < 4; ++i)
        v[i] = (_Float16)((K == J && (4 * h + i) == c) ? 1.0f : 0.0f);
      bf[K][J] = v;
    }

  float Lacc = 0.f;
  f4 LB0[4][4], LB1[4][4];
  h4 af[4][4];

#define LOADE(LB, S)                                                         \
  do { const float* ep = eb + (size_t)(S) * LL;                              \
    _Pragma("unroll") for (int I = 0; I < 4; ++I) {                          \
      const float* rp = ep + (16 * I + c) * 64 + 4 * h;                      \
      _Pragma("unroll") for (int K = 0; K < 4; ++K)                          \
        LB[I][K] = *reinterpret_cast<const f4*>(rp + 16 * K);                \
    } } while (0)

#define BUILDAF(LB)                                                          \
  do { _Pragma("unroll") for (int I = 0; I < 4; ++I)                         \
    _Pragma("unroll") for (int K = 0; K < 4; ++K) {                          \
      U4 x;                                                                  \
      x.u[0] = pk2(expw(LB[I][K][0]), expw(LB[I][K][1]));                    \
      x.u[1] = pk2(expw(LB[I][K][2]), expw(LB[I][K][3]));                    \
      af[I][K] = x.v;                                                        \
    } } while (0)

#define STEPM(LBC, M)                                                        \
  do { if ((M) <= n) {                                                       \
    BUILDAF(LBC);                                                            \
    if ((M) + 2 <= n) LOADE(LBC, s0 + n - 2 - (M));                          \
    const bool rn = ((M) == n);                                              \
    float mh = 0.f;                                                          \
    { /* half 0: J in {0,1} */                                               \
      f4 dh[4][2];                                                           \
      _Pragma("unroll") for (int I = 0; I < 4; ++I)                          \
        _Pragma("unroll") for (int J = 0; J < 2; ++J) {                      \
          f4 d = {0.f, 0.f, 0.f, 0.f};                                       \
          _Pragma("unroll") for (int K = 0; K < 4; ++K)                      \
            d = __builtin_amdgcn_mfma_f32_16x16x16f16(af[I][K], bf[K][J], d, 0, 0, 0); \
          dh[I][J] = d;                                                      \
        }                                                                    \
      if (rn) {                                                              \
        _Pragma("unroll") for (int I = 0; I < 4; ++I)                        \
          _Pragma("unroll") for (int J = 0; J < 2; ++J)                      \
            _Pragma("unroll") for (int u = 0; u < 4; ++u)                    \
              mh = fmaxf(mh, dh[I][J][u]);                                   \
      }                                                                      \
      _Pragma("unroll") for (int K = 0; K < 4; ++K)                          \
        _Pragma("unroll") for (int J = 0; J < 2; ++J) {                      \
          U4 y;                                                              \
          y.u[0] = pk2(dh[K][J][0], dh[K][J][1]);                            \
          y.u[1] = pk2(dh[K][J][2], dh[K][J][3]);                            \
          bf[K][J] = y.v;                                                    \
        }                                                                    \
    }                                                                        \
    { /* half 1: J in {2,3} */                                               \
      f4 dh[4][2];                                                           \
      _Pragma("unroll") for (int I = 0; I < 4; ++I)                          \
        _Pragma("unroll") for (int J = 0; J < 2; ++J) {                      \
          f4 d = {0.f, 0.f, 0.f, 0.f};                                       \
          _Pragma("unroll") for (int K = 0; K < 4; ++K)                      \
            d = __builtin_amdgcn_mfma_f32_16x16x16f16(af[I][K], bf[K][J + 2], d, 0, 0, 0); \
          dh[I][J] = d;                                                      \
        }                                                                    \
      if (rn) {                                                              \
        _Pragma("unroll") for (int I = 0; I < 4; ++I)                        \
          _Pragma("unroll") for (int J = 0; J < 2; ++J)                      \
            _Pragma("unroll") for (int u = 0; u < 4; ++u)                    \
              mh = fmaxf(mh, dh[I][J][u]);                                   \
      }                                                                      \
      _Pragma("unroll") for (int K = 0; K < 4; ++K)                          \
        _Pragma("unroll") for (int J = 0; J < 2; ++J) {                      \
          U4 y;                                                              \
          y.u[0] = pk2(dh[K][J][0], dh[K][J][1]);                            \
          y.u[1] = pk2(dh[K][J][2], dh[K][J][3]);                            \
          bf[K][J + 2] = y.v;                                                \
        }                                                                    \
    }                                                                        \
    Lacc += PREF;                                                            \
    if (rn) {                                                                \
      _Pragma("unroll") for (int off = 32; off; off >>= 1)                   \
        mh = fmaxf(mh, __shfl_xor(mh, off));                                 \
      const int E = (__float_as_int(mh) >> 23) & 0xFF;                       \
      const _Float16 hs = (_Float16)__int_as_float((254 - E) << 23);         \
      const h4 hv = {hs, hs, hs, hs};                                        \
      _Pragma("unroll") for (int K = 0; K < 4; ++K)                          \
        _Pragma("unroll") for (int J = 0; J < 4; ++J) bf[K][J] *= hv;        \
      Lacc += (float)(E - 127) * LN2F;                                       \
    }                                                                        \
  } } while (0)

  LOADE(LB0, s0 + n - 1);              // step-1 matrix (s descending)
  if (n > 1) LOADE(LB1, s0 + n - 2);   // step-2 matrix
  for (int m = 1; m <= n; m += 2) {
    STEPM(LB0, m);
    STEPM(LB1, m + 1);
  }

  // store R = P^T (B-frag layout)
  {
    _Float16* mp = matP + (size_t)ci * 4096;
    #pragma unroll
    for (int I = 0; I < 4; ++I)
      #pragma unroll
      for (int J = 0; J < 4; ++J)
        #pragma unroll
        for (int i = 0; i < 4; ++i)
          mp[(I * 4 + J) * 256 + i * 64 + lane] = bf[I][J][i];
  }
  if (lane == 0) wsf[ci] = Lacc;
}

// ---------------- Phase 2: fold chunks into alpha0 (+ fused finale) --------
__global__ __launch_bounds__(64) void crf_fold(
    const float* __restrict__ emits,
    const int*   __restrict__ mask,
    const _Float16* __restrict__ matP,
    const float* __restrict__ wsf,
    float*       __restrict__ wso,   // [0,32): logz ; [32,64): len
    int*         __restrict__ done,
    float*       __restrict__ out)
{
  const int b = blockIdx.x, lane = threadIdx.x;
  const int c = lane & 15, h = lane >> 4;
  const float* __restrict__ eb = emits + (size_t)b * (S_LEN * LL);

  int len;
  {
    const int* mb = mask + b * S_LEN;
    int cnt = 0;
    #pragma unroll
    for (int i = 0; i < 8; ++i) cnt += (mb[i * 64 + lane] != 0);
    #pragma unroll
    for (int off = 32; off; off >>= 1) cnt += __shfl_xor(cnt, off);
    len = cnt;
  }
  const int nact = (len + CL - 2) >> 3;   // chunks with >=1 matrix (len>=2)

  const bool on = (c == 0);
  const h4 HZ = {(_Float16)0, (_Float16)0, (_Float16)0, (_Float16)0};

  // alpha0[k] = E_0[BOS=0][k]
  float la[16];
  #pragma unroll
  for (int K = 0; K < 4; ++K)
    #pragma unroll
    for (int i = 0; i < 4; ++i) la[K * 4 + i] = eb[16 * K + 4 * h + i];
  float mm = la[0];
  #pragma unroll
  for (int i = 1; i < 16; ++i) mm = fmaxf(mm, la[i]);
  const float m0 = fmaxf(fmaxf(bl(mm, 0), bl(mm, 16)), fmaxf(bl(mm, 32), bl(mm, 48)));
  float Lacc = m0;
  h4 bv[4];
  #pragma unroll
  for (int K = 0; K < 4; ++K) {
    U4 y;
    y.u[0] = pk2(__expf(la[4 * K] - m0), __expf(la[4 * K + 1] - m0));
    y.u[1] = pk2(__expf(la[4 * K + 2] - m0), __expf(la[4 * K + 3] - m0));
    bv[K] = on ? y.v : HZ;
  }

  h4 A0[4][4], A1[4][4], A2[4][4], A3[4][4];   // depth-4 prefetch ring

#define LOADA(AF, CH)                                                        \
  do { const _Float16* mp = matP + (size_t)(b * NCH + (CH)) * 4096;          \
    _Pragma("unroll") for (int I = 0; I < 4; ++I)                            \
      _Pragma("unroll") for (int K = 0; K < 4; ++K)                          \
        AF[I][K] = *reinterpret_cast<const h4*>(                             \
            mp + (I * 4 + K) * 256 + (c & 3) * 64 + 16 * (c >> 2) + 4 * h);  \
  } while (0)

#define FOLD(AF, CH)                                                         \
  do { f4 dv[4];                                                             \
    _Pragma("unroll") for (int I = 0; I < 4; ++I) {                          \
      f4 d = {0.f, 0.f, 0.f, 0.f};                                           \
      _Pragma("unroll") for (int K = 0; K < 4; ++K)                          \
        d = __builtin_amdgcn_mfma_f32_16x16x16f16(AF[I][K], bv[K], d, 0, 0, 0); \
      dv[I] = d;                                                             \
    }                                                                        \
    float mx = dv[0][0];                                                     \
    _Pragma("unroll") for (int I = 0; I < 4; ++I)                            \
      _Pragma("unroll") for (int u = 0; u < 4; ++u) mx = fmaxf(mx, dv[I][u]); \
    float gm;                                                                \
    if (((CH) & 3) == 3) {                                                   \
      gm = fmaxf(fmaxf(bl(mx, 0), bl(mx, 16)),                               \
                 fmaxf(bl(mx, 32), bl(mx, 48)));                             \
    } else {                                                                 \
      gm = bl(mx, 0);                                                        \
    }                                                                        \
    const int E = (__float_as_int(gm) >> 23) & 0xFF;                         \
    const float scale = __int_as_float((254 - E) << 23);                     \
    Lacc += (float)(E - 127) * LN2F + wsf[b * NCH + (CH)];                   \
    _Pragma("unroll") for (int I = 0; I < 4; ++I) {                          \
      U4 y;                                                                  \
      y.u[0] = pk2(dv[I][0] * scale, dv[I][1] * scale);                      \
      y.u[1] = pk2(dv[I][2] * scale, dv[I][3] * scale);                      \
      bv[I] = on ? y.v : HZ;                                                 \
    } } while (0)

#define FSTEP(AF, APre, CH)                                                  \
  do { if ((CH) < nact) {                                                    \
    if ((CH) + 3 < nact) LOADA(APre, (CH) + 3);                              \
    FOLD(AF, (CH));                                                          \
  } } while (0)

  LOADA(A0, 0);
  if (1 < nact) LOADA(A1, 1);
  if (2 < nact) LOADA(A2, 2);
  for (int ch = 0; ch < nact; ch += 4) {
    FSTEP(A0, A3, ch);
    FSTEP(A1, A0, ch + 1);
    FSTEP(A2, A1, ch + 2);
    FSTEP(A3, A2, ch + 3);
  }

  float qs = 0.f;
  #pragma unroll
  for (int K = 0; K < 4; ++K)
    #pragma unroll
    for (int i = 0; i < 4; ++i) qs += (float)bv[K][i];
  const float q0 = (bl(qs, 0) + bl(qs, 16)) + (bl(qs, 32) + bl(qs, 48));
  if (lane == 0) {
    wso[b]      = Lacc + __logf(q0);
    wso[32 + b] = (float)len;
  }

  // ---- fused finale: last block to finish reduces everything ----
  __threadfence();
  int isLast = 0;
  if (lane == 0) isLast = (atomicAdd(done, 1) == NB - 1);
  isLast = __shfl(isLast, 0);
  if (isLast) {
    __threadfence();
    const float* gold = wsf + NCHUNKS;
    float gs = 0.f;
    #pragma unroll
    for (int i = 0; i < NCHUNKS / 64; ++i) gs += gold[i * 64 + lane];
    float lz = (lane < NB) ? wso[lane] : 0.f;
    float ln = (lane < NB) ? wso[32 + lane] : 0.f;
    #pragma unroll
    for (int off = 32; off; off >>= 1) {
      gs += __shfl_xor(gs, off);
      lz += __shfl_xor(lz, off);
      ln += __shfl_xor(ln, off);
    }
    if (lane == 0) out[0] = (lz - gs) / ln;
  }
}

extern "C" void kernel_launch(void* const* d_in, const int* in_sizes, int n_in,
                              void* d_out, int out_size, void* d_ws, size_t ws_size,
                              hipStream_t stream) {
  const float* emits   = (const float*)d_in[0];
  const int*   targets = (const int*)d_in[1];
  const int*   mask    = (const int*)d_in[2];
  float* out = (float*)d_out;

  _Float16* matP = (_Float16*)d_ws;                                   // 16 MB
  float*    wsf  = (float*)((char*)d_ws + (size_t)NCHUNKS * 4096 * 2);
  float*    wso  = wsf + 2 * NCHUNKS;
  int*      done = (int*)(wso + 64);

  hipMemsetAsync(done, 0, sizeof(int), stream);
  hipLaunchKernelGGL(crf_chunk, dim3(NCHUNKS), dim3(64), 0, stream,
                     emits, targets, mask, matP, wsf);
  hipLaunchKernelGGL(crf_fold, dim3(NB), dim3(64), 0, stream,
                     emits, mask, matP, wsf, wso, done, out);
}

// Round 15
// 75.084 us; speedup vs baseline: 1.3381x; 1.3381x over previous
//
#include <hip/hip_runtime.h>
#include <math.h>

// CRF forward loss, B=32, S=512, L=64 — chunked-matrix-product formulation.
// Round 15: HBM-granularity fix. R12 profile implies the chunk phase is
// capped ~2.2 TB/s by scattered-64B fragment loads (16 rows/instr). New:
// stage each 16KB matrix to LDS via 16x global_load_lds (contiguous 1KB
// per instr = the 6.3TB/s ubench pattern), pre-swizzled global source
// (sub ^= row&7, within-row -> coalescing kept), swizzled ds_read_b128
// fragment reads (conflict-free). Counted vmcnt(16); lgkmcnt(0) WAR guard.

constexpr int S_LEN   = 512;
constexpr int NB      = 32;
constexpr int NL      = 64;
constexpr int LL      = 4096;
constexpr int CL      = 16;
constexpr int NCH     = 32;            // chunks per batch
constexpr int NCHUNKS = NB * NCH;      // 1024

#define LN2F 0.69314718055994531f
#define PREF 4.6588830833596715f       /* ln(64)+0.5 : M = exp(E)*e^-PREF */

typedef _Float16 h4 __attribute__((ext_vector_type(4)));
typedef float    f4 __attribute__((ext_vector_type(4)));
union U4 { unsigned u[2]; h4 v; };

__device__ __forceinline__ float bl(float v, int sl) {
  return __int_as_float(__builtin_amdgcn_readlane(__float_as_int(v), sl));
}
__device__ __forceinline__ unsigned pk2(float a, float b) {
  auto r = __builtin_amdgcn_cvt_pkrtz(a, b);
  return __builtin_bit_cast(unsigned, r);
}
__device__ __forceinline__ float expw(float x) {   // exp(x)*e^-PREF, native
  return __expf(x - PREF);
}
__device__ __forceinline__ void gld16(const void* g, void* l) {
  __builtin_amdgcn_global_load_lds(
      (const __attribute__((address_space(1))) unsigned*)g,
      (__attribute__((address_space(3))) unsigned*)l, 16, 0, 0);
}

// ---------------- Phase 1: chunk products (backward, LDS-staged) ------------
__global__ __launch_bounds__(64) void crf_chunk(
    const float* __restrict__ emits,
    const int*   __restrict__ targets,
    const int*   __restrict__ mask,
    _Float16*    __restrict__ matP,   // [1024][4096] f16
    float*       __restrict__ wsf)    // [0,1024): Lacc ; [1024,2048): gold
{
  __shared__ float ring[2][4096];     // 2 x 16KB slots

  const int ci   = blockIdx.x;
  const int b    = ci >> 5;
  const int cc   = ci & 31;
  const int lane = threadIdx.x;
  const int c    = lane & 15;
  const int h    = lane >> 4;
  const float* __restrict__ eb = emits + (size_t)b * (S_LEN * LL);

  // sequence length (mask is a contiguous prefix)
  int len;
  {
    const int* mb = mask + b * S_LEN;
    int cnt = 0;
    #pragma unroll
    for (int i = 0; i < 8; ++i) cnt += (mb[i * 64 + lane] != 0);
    #pragma unroll
    for (int off = 32; off; off >>= 1) cnt += __shfl_xor(cnt, off);
    len = cnt;
  }

  // gold partial: emissions s in [16cc, 16cc+16) ∩ [0,len)
  {
    float g = 0.f;
    const int s = 16 * cc + (lane & 15);
    if (lane < 16 && s < len) {
      const int* tb = targets + b * (S_LEN + 1);
      g = eb[(size_t)s * LL + tb[s] * NL + tb[s + 1]];
    }
    #pragma unroll
    for (int off = 32; off; off >>= 1) g += __shfl_xor(g, off);
    if (lane == 0) wsf[NCHUNKS + ci] = g;
  }

  const int s0 = 16 * cc + 1;
  const int n  = min(len - s0, CL);
  if (n < 1) return;

  // Pre-swizzled per-lane source byte offsets for the staging DMA.
  // Instr q covers rows 4q..4q+3; lane l -> row 4q+(l>>4), dest sub' = l&15.
  // Stored[row][sub'] = logical[row][sub' ^ (row&7)], row&7 = (l>>4)+4*(q&1).
  const int pe = h * 256 + ((c ^ h) * 16);        // q even
  const int po = h * 256 + ((c ^ (h + 4)) * 16);  // q odd

#define STAGE(SLOT, S)                                                       \
  do { const char* mbase = (const char*)(eb + (size_t)(S) * LL);             \
    char* lbase = (char*)&ring[SLOT][0];                                     \
    _Pragma("unroll") for (int q = 0; q < 16; ++q) {                         \
      gld16(mbase + q * 1024 + ((q & 1) ? po : pe), lbase + q * 1024);       \
    } } while (0)

  // R = Identity in B-frag layout
  h4 bf[4][4];
  #pragma unroll
  for (int K = 0; K < 4; ++K)
    #pragma unroll
    for (int J = 0; J < 4; ++J) {
      h4 v;
      #pragma unroll
      for (int i = 0; i < 4; ++i)
        v[i] = (_Float16)((K == J && (4 * h + i) == c) ? 1.0f : 0.0f);
      bf[K][J] = v;
    }

  float Lacc = 0.f;
  h4 af[4][4];

  // af tile(I,K): logical row 16I+c, sub 4K+h -> stored sub (4K+h)^(c&7)
#define BUILDAF(SLOT)                                                        \
  do { const char* Wb = (const char*)&ring[SLOT][0];                         \
    _Pragma("unroll") for (int I = 0; I < 4; ++I)                            \
      _Pragma("unroll") for (int K = 0; K < 4; ++K) {                        \
        f4 t = *(const f4*)(Wb + (16 * I + c) * 256 +                        \
                            (((4 * K + h) ^ (c & 7)) * 16));                 \
        U4 x;                                                                \
        x.u[0] = pk2(expw(t[0]), expw(t[1]));                                \
        x.u[1] = pk2(expw(t[2]), expw(t[3]));                                \
        af[I][K] = x.v;                                                      \
      } } while (0)

#define STEPM(M)                                                             \
  do { if ((M) <= n) {                                                       \
    if ((M) == n) { asm volatile("s_waitcnt vmcnt(0)" ::: "memory"); }       \
    else          { asm volatile("s_waitcnt vmcnt(16)" ::: "memory"); }      \
    __builtin_amdgcn_sched_barrier(0);                                       \
    BUILDAF(((M) - 1) & 1);                                                  \
    asm volatile("s_waitcnt lgkmcnt(0)" ::: "memory");   /* WAR: DMA vs ds_read */ \
    __builtin_amdgcn_sched_barrier(0);                                       \
    if ((M) + 2 <= n) STAGE(((M) - 1) & 1, s0 + n - 2 - (M));                \
    const bool rn = ((((M) & 7) == 0) || ((M) == n));                        \
    float mh = 0.f;                                                          \
    { /* half 0: J in {0,1} */                                               \
      f4 dh[4][2];                                                           \
      _Pragma("unroll") for (int I = 0; I < 4; ++I)                          \
        _Pragma("unroll") for (int J = 0; J < 2; ++J) {                      \
          f4 d = {0.f, 0.f, 0.f, 0.f};                                       \
          _Pragma("unroll") for (int K = 0; K < 4; ++K)                      \
            d = __builtin_amdgcn_mfma_f32_16x16x16f16(af[I][K], bf[K][J], d, 0, 0, 0); \
          dh[I][J] = d;                                                      \
        }                                                                    \
      if (rn) {                                                              \
        _Pragma("unroll") for (int I = 0; I < 4; ++I)                        \
          _Pragma("unroll") for (int J = 0; J < 2; ++J)                      \
            _Pragma("unroll") for (int u = 0; u < 4; ++u)                    \
              mh = fmaxf(mh, dh[I][J][u]);                                   \
      }                                                                      \
      _Pragma("unroll") for (int K = 0; K < 4; ++K)                          \
        _Pragma("unroll") for (int J = 0; J < 2; ++J) {                      \
          U4 y;                                                              \
          y.u[0] = pk2(dh[K][J][0], dh[K][J][1]);                            \
          y.u[1] = pk2(dh[K][J][2], dh[K][J][3]);                            \
          bf[K][J] = y.v;                                                    \
        }                                                                    \
    }                                                                        \
    { /* half 1: J in {2,3} */                                               \
      f4 dh[4][2];                                                           \
      _Pragma("unroll") for (int I = 0; I < 4; ++I)                          \
        _Pragma("unroll") for (int J = 0; J < 2; ++J) {                      \
          f4 d = {0.f, 0.f, 0.f, 0.f};                                       \
          _Pragma("unroll") for (int K = 0; K < 4; ++K)                      \
            d = __builtin_amdgcn_mfma_f32_16x16x16f16(af[I][K], bf[K][J + 2], d, 0, 0, 0); \
          dh[I][J] = d;                                                      \
        }                                                                    \
      if (rn) {                                                              \
        _Pragma("unroll") for (int I = 0; I < 4; ++I)                        \
          _Pragma("unroll") for (int J = 0; J < 2; ++J)                      \
            _Pragma("unroll") for (int u = 0; u < 4; ++u)                    \
              mh = fmaxf(mh, dh[I][J][u]);                                   \
      }                                                                      \
      _Pragma("unroll") for (int K = 0; K < 4; ++K)                          \
        _Pragma("unroll") for (int J = 0; J < 2; ++J) {                      \
          U4 y;                                                              \
          y.u[0] = pk2(dh[K][J][0], dh[K][J][1]);                            \
          y.u[1] = pk2(dh[K][J][2], dh[K][J][3]);                            \
          bf[K][J + 2] = y.v;                                                \
        }                                                                    \
    }                                                                        \
    Lacc += PREF;                                                            \
    if (rn) {                                                                \
      _Pragma("unroll") for (int off = 32; off; off >>= 1)                   \
        mh = fmaxf(mh, __shfl_xor(mh, off));                                 \
      const int E = (__float_as_int(mh) >> 23) & 0xFF;                       \
      const _Float16 hs = (_Float16)__int_as_float((254 - E) << 23);         \
      const h4 hv = {hs, hs, hs, hs};                                        \
      _Pragma("unroll") for (int K = 0; K < 4; ++K)                          \
        _Pragma("unroll") for (int J = 0; J < 4; ++J) bf[K][J] *= hv;        \
      Lacc += (float)(E - 127) * LN2F;                                       \
    }                                                                        \
  } } while (0)

  STAGE(0, s0 + n - 1);                // step-1 matrix (s descending)
  if (n > 1) STAGE(1, s0 + n - 2);     // step-2 matrix
  for (int m = 1; m <= n; m += 2) {
    STEPM(m);
    STEPM(m + 1);
  }

  // store R = P^T (B-frag layout)
  {
    _Float16* mp = matP + (size_t)ci * 4096;
    #pragma unroll
    for (int I = 0; I < 4; ++I)
      #pragma unroll
      for (int J = 0; J < 4; ++J)
        #pragma unroll
        for (int i = 0; i < 4; ++i)
          mp[(I * 4 + J) * 256 + i * 64 + lane] = bf[I][J][i];
  }
  if (lane == 0) wsf[ci] = Lacc;
}

// ---------------- Phase 2: fold chunks into alpha0 (+ fused finale) --------
__global__ __launch_bounds__(64) void crf_fold(
    const float* __restrict__ emits,
    const int*   __restrict__ mask,
    const _Float16* __restrict__ matP,
    const float* __restrict__ wsf,
    float*       __restrict__ wso,   // [0,32): logz ; [32,64): len
    int*         __restrict__ done,
    float*       __restrict__ out)
{
  const int b = blockIdx.x, lane = threadIdx.x;
  const int c = lane & 15, h = lane >> 4;
  const float* __restrict__ eb = emits + (size_t)b * (S_LEN * LL);

  int len;
  {
    const int* mb = mask + b * S_LEN;
    int cnt = 0;
    #pragma unroll
    for (int i = 0; i < 8; ++i) cnt += (mb[i * 64 + lane] != 0);
    #pragma unroll
    for (int off = 32; off; off >>= 1) cnt += __shfl_xor(cnt, off);
    len = cnt;
  }
  const int nact = (len + 14) >> 4;   // chunks with >=1 matrix (len>=2)

  const bool on = (c == 0);
  const h4 HZ = {(_Float16)0, (_Float16)0, (_Float16)0, (_Float16)0};

  // alpha0[k] = E_0[BOS=0][k]
  float la[16];
  #pragma unroll
  for (int K = 0; K < 4; ++K)
    #pragma unroll
    for (int i = 0; i < 4; ++i) la[K * 4 + i] = eb[16 * K + 4 * h + i];
  float mm = la[0];
  #pragma unroll
  for (int i = 1; i < 16; ++i) mm = fmaxf(mm, la[i]);
  const float m0 = fmaxf(fmaxf(bl(mm, 0), bl(mm, 16)), fmaxf(bl(mm, 32), bl(mm, 48)));
  float Lacc = m0;
  h4 bv[4];
  #pragma unroll
  for (int K = 0; K < 4; ++K) {
    U4 y;
    y.u[0] = pk2(__expf(la[4 * K] - m0), __expf(la[4 * K + 1] - m0));
    y.u[1] = pk2(__expf(la[4 * K + 2] - m0), __expf(la[4 * K + 3] - m0));
    bv[K] = on ? y.v : HZ;
  }

  h4 A0[4][4], A1[4][4];

#define LOADA(AF, CH)                                                        \
  do { const _Float16* mp = matP + (size_t)(b * NCH + (CH)) * 4096;          \
    _Pragma("unroll") for (int I = 0; I < 4; ++I)                            \
      _Pragma("unroll") for (int K = 0; K < 4; ++K)                          \
        AF[I][K] = *reinterpret_cast<const h4*>(                             \
            mp + (I * 4 + K) * 256 + (c & 3) * 64 + 16 * (c >> 2) + 4 * h);  \
  } while (0)

#define FOLD(AF, CH)                                                         \
  do { f4 dv[4];                                                             \
    _Pragma("unroll") for (int I = 0; I < 4; ++I) {                          \
      f4 d = {0.f, 0.f, 0.f, 0.f};                                           \
      _Pragma("unroll") for (int K = 0; K < 4; ++K)                          \
        d = __builtin_amdgcn_mfma_f32_16x16x16f16(AF[I][K], bv[K], d, 0, 0, 0); \
      dv[I] = d;                                                             \
    }                                                                        \
    float mx = dv[0][0];                                                     \
    _Pragma("unroll") for (int I = 0; I < 4; ++I)                            \
      _Pragma("unroll") for (int u = 0; u < 4; ++u) mx = fmaxf(mx, dv[I][u]); \
    float gm;                                                                \
    if (((CH) & 3) == 3) {                                                   \
      gm = fmaxf(fmaxf(bl(mx, 0), bl(mx, 16)),                               \
                 fmaxf(bl(mx, 32), bl(mx, 48)));                             \
    } else {                                                                 \
      gm = bl(mx, 0);                                                        \
    }                                                                        \
    const int E = (__float_as_int(gm) >> 23) & 0xFF;                         \
    const float scale = __int_as_float((254 - E) << 23);                     \
    Lacc += (float)(E - 127) * LN2F + wsf[b * NCH + (CH)];                   \
    _Pragma("unroll") for (int I = 0; I < 4; ++I) {                          \
      U4 y;                                                                  \
      y.u[0] = pk2(dv[I][0] * scale, dv[I][1] * scale);                      \
      y.u[1] = pk2(dv[I][2] * scale, dv[I][3] * scale);                      \
      bv[I] = on ? y.v : HZ;                                                 \
    } } while (0)

  LOADA(A0, 0);
  for (int ch = 0; ch < nact; ++ch) {
    if (ch & 1) { if (ch + 1 < nact) LOADA(A0, ch + 1); FOLD(A1, ch); }
    else        { if (ch + 1 < nact) LOADA(A1, ch + 1); FOLD(A0, ch); }
  }

  float qs = 0.f;
  #pragma unroll
  for (int K = 0; K < 4; ++K)
    #pragma unroll
    for (int i = 0; i < 4; ++i) qs += (float)bv[K][i];
  const float q0 = (bl(qs, 0) + bl(qs, 16)) + (bl(qs, 32) + bl(qs, 48));
  if (lane == 0) {
    wso[b]      = Lacc + __logf(q0);
    wso[32 + b] = (float)len;
  }

  // ---- fused finale: last block to finish reduces everything ----
  __threadfence();
  int isLast = 0;
  if (lane == 0) isLast = (atomicAdd(done, 1) == NB - 1);
  isLast = __shfl(isLast, 0);
  if (isLast) {
    __threadfence();
    const float* gold = wsf + NCHUNKS;
    float gs = 0.f;
    #pragma unroll
    for (int i = 0; i < NCHUNKS / 64; ++i) gs += gold[i * 64 + lane];
    float lz = (lane < NB) ? wso[lane] : 0.f;
    float ln = (lane < NB) ? wso[32 + lane] : 0.f;
    #pragma unroll
    for (int off = 32; off; off >>= 1) {
      gs += __shfl_xor(gs, off);
      lz += __shfl_xor(lz, off);
      ln += __shfl_xor(ln, off);
    }
    if (lane == 0) out[0] = (lz - gs) / ln;
  }
}

extern "C" void kernel_launch(void* const* d_in, const int* in_sizes, int n_in,
                              void* d_out, int out_size, void* d_ws, size_t ws_size,
                              hipStream_t stream) {
  const float* emits   = (const float*)d_in[0];
  const int*   targets = (const int*)d_in[1];
  const int*   mask    = (const int*)d_in[2];
  float* out = (float*)d_out;

  _Float16* matP = (_Float16*)d_ws;                                   // 8 MB
  float*    wsf  = (float*)((char*)d_ws + (size_t)NCHUNKS * 4096 * 2);
  float*    wso  = wsf + 2 * NCHUNKS;
  int*      done = (int*)(wso + 64);

  hipMemsetAsync(done, 0, sizeof(int), stream);
  hipLaunchKernelGGL(crf_chunk, dim3(NCHUNKS), dim3(64), 0, stream,
                     emits, targets, mask, matP, wsf);
  hipLaunchKernelGGL(crf_fold, dim3(NB), dim3(64), 0, stream,
                     emits, mask, matP, wsf, wso, done, out);
}